// Round 1
// baseline (128.206 us; speedup 1.0000x reference)
//
#include <hip/hip_runtime.h>

// ---------------- sizes ----------------
#define BATCH 4096
#define IN_DIM 512
#define H1DIM 128
#define H2DIM 64
#define DDIM 64
#define NFUNC 2081
#define NFPAD 2112   // padded to multiple of 32

// ---------------- dual-GEMM tile config ----------------
#define NT 256
#define BM 32
#define BN 64
#define BK 32
#define TM 2
#define TN 4

// =====================================================================
// init: triu index tables (with bias/linear/pad sentinels) + XI*XI_mask
// =====================================================================
__global__ void init_tables(int* __restrict__ iu, int* __restrict__ ju,
                            float* __restrict__ xi_eff,
                            const float* __restrict__ XI,
                            const float* __restrict__ XIm)
{
    int gid = blockIdx.x * blockDim.x + threadIdx.x;
    if (gid < NFPAD) {
        int a, b;
        if (gid == 0) { a = 64; b = 64; }            // bias: zs[..][64]=1
        else if (gid <= DDIM) { a = gid - 1; b = 64; } // linear term
        else if (gid < NFUNC) {
            int p = gid - 1 - DDIM;
            int i = 0, cum = 0;
            while (cum + (63 - i) <= p) { cum += 63 - i; ++i; }
            a = i; b = i + 1 + (p - cum);
        } else { a = 65; b = 65; }                   // pad: zs[..][65]=0
        iu[gid] = a; ju[gid] = b;
    }
    // xi_eff = XI * XI_mask, padded rows zeroed. One float4 per thread.
    if (gid < NFPAD * 16) {
        int f = gid >> 4;
        int c = (gid & 15) << 2;
        float4 v;
        if (f < NFUNC) {
            const float4 a = *(const float4*)&XI[f * DDIM + c];
            const float4 m = *(const float4*)&XIm[f * DDIM + c];
            v = make_float4(a.x * m.x, a.y * m.y, a.z * m.z, a.w * m.w);
        } else {
            v = make_float4(0.f, 0.f, 0.f, 0.f);
        }
        *(float4*)&xi_eff[f * DDIM + c] = v;
    }
}

// =====================================================================
// dual GEMM: H = relu(A @ W^T + bias), V = (pre>0) ? (Av @ W^T) : 0
// A,Av: [M,K] row-major; W: [N,K] (torch Linear layout); H,V: [M,N]
// SUM4: Av is 4 stacked partials [4][M*K] summed on load; the sum is
// also written to vsum_out (used for decL1: Av = dz_dt_sindy output).
// =====================================================================
template<bool SUM4>
__global__ __launch_bounds__(NT)
void dual_gemm(const float* __restrict__ A, const float* __restrict__ Av,
               const float* __restrict__ W, const float* __restrict__ bias,
               float* __restrict__ H, float* __restrict__ V,
               float* __restrict__ vsum_out,
               int M, int N, int K, int partStride)
{
    __shared__ float AsT[BK][BM];   // k-major (transposed)
    __shared__ float AvT[BK][BM];
    __shared__ float WT[BK][BN];

    const int tid = threadIdx.x;
    const int row0 = blockIdx.x * BM;
    const int col0 = blockIdx.y * BN;
    const int rg = tid >> 4;            // 0..15
    const int cg = tid & 15;            // 0..15
    const int r0 = rg * TM;
    const int c0 = cg * TN;

    // staging indices (A/Av): 32 rows x 8 quads
    const int sr = tid >> 3;            // 0..31
    const int sk = (tid & 7) << 2;      // 0,4,..,28

    float acc_h[TM][TN] = {};
    float acc_v[TM][TN] = {};

    for (int k0 = 0; k0 < K; k0 += BK) {
        // ---- stage A, Av (transpose into k-major LDS) ----
        const size_t abase = (size_t)(row0 + sr) * K + k0 + sk;
        float4 a4 = *(const float4*)&A[abase];
        float4 av4;
        if constexpr (SUM4) {
            float4 s0 = *(const float4*)&Av[abase];
            float4 s1 = *(const float4*)&Av[abase + (size_t)partStride];
            float4 s2 = *(const float4*)&Av[abase + (size_t)2 * partStride];
            float4 s3 = *(const float4*)&Av[abase + (size_t)3 * partStride];
            av4 = make_float4(s0.x + s1.x + s2.x + s3.x,
                              s0.y + s1.y + s2.y + s3.y,
                              s0.z + s1.z + s2.z + s3.z,
                              s0.w + s1.w + s2.w + s3.w);
            *(float4*)&vsum_out[abase] = av4;   // emit dz_dt_sindy
        } else {
            av4 = *(const float4*)&Av[abase];
        }
        AsT[sk + 0][sr] = a4.x;  AsT[sk + 1][sr] = a4.y;
        AsT[sk + 2][sr] = a4.z;  AsT[sk + 3][sr] = a4.w;
        AvT[sk + 0][sr] = av4.x; AvT[sk + 1][sr] = av4.y;
        AvT[sk + 2][sr] = av4.z; AvT[sk + 3][sr] = av4.w;

        // ---- stage W ----
        #pragma unroll
        for (int it = 0; it < 2; ++it) {
            int L = tid + it * NT;
            int wc = L >> 3;            // 0..63
            int wk = (L & 7) << 2;
            float4 w4 = *(const float4*)&W[(size_t)(col0 + wc) * K + k0 + wk];
            WT[wk + 0][wc] = w4.x; WT[wk + 1][wc] = w4.y;
            WT[wk + 2][wc] = w4.z; WT[wk + 3][wc] = w4.w;
        }
        __syncthreads();

        // ---- inner product ----
        #pragma unroll
        for (int kk = 0; kk < BK; ++kk) {
            float2 a2  = *(const float2*)&AsT[kk][r0];
            float2 av2 = *(const float2*)&AvT[kk][r0];
            float4 w4  = *(const float4*)&WT[kk][c0];
            float wv[TN] = { w4.x, w4.y, w4.z, w4.w };
            float aa[TM] = { a2.x, a2.y };
            float vv[TM] = { av2.x, av2.y };
            #pragma unroll
            for (int t = 0; t < TM; ++t)
                #pragma unroll
                for (int u = 0; u < TN; ++u) {
                    acc_h[t][u] = fmaf(aa[t], wv[u], acc_h[t][u]);
                    acc_v[t][u] = fmaf(vv[t], wv[u], acc_v[t][u]);
                }
        }
        __syncthreads();
    }

    // ---- epilogue: bias, relu, mask ----
    const float4 b4 = *(const float4*)&bias[col0 + c0];
    const float bv[TN] = { b4.x, b4.y, b4.z, b4.w };
    #pragma unroll
    for (int t = 0; t < TM; ++t) {
        const int row = row0 + r0 + t;
        float h[TN], v[TN];
        #pragma unroll
        for (int u = 0; u < TN; ++u) {
            const float pre = acc_h[t][u] + bv[u];
            h[u] = pre > 0.f ? pre : 0.f;
            v[u] = pre > 0.f ? acc_v[t][u] : 0.f;
        }
        *(float4*)&H[(size_t)row * N + col0 + c0] = make_float4(h[0], h[1], h[2], h[3]);
        *(float4*)&V[(size_t)row * N + col0 + c0] = make_float4(v[0], v[1], v[2], v[3]);
    }
}

// =====================================================================
// SINDy library GEMM (split-K=4): part[ks] += theta(z) @ xi_eff over the
// ks-th chunk of functions. theta generated on the fly from z tile.
// =====================================================================
#define S_BM 32
#define S_BK 32
#define S_NT 128
#define NCHUNK (NFPAD / S_BK)   // 66

__global__ __launch_bounds__(S_NT)
void sindy_gemm(const float* __restrict__ z, const float* __restrict__ xi,
                const int* __restrict__ iu, const int* __restrict__ ju,
                float* __restrict__ part)
{
    __shared__ float zs[S_BM][66];      // cols 0..63 = z, 64 = 1, 65 = 0
    __shared__ float ThT[S_BK][S_BM];   // theta transposed (k-major)
    __shared__ float XiS[S_BK][64];

    const int tid = threadIdx.x;
    const int row0 = blockIdx.x * S_BM;
    const int ks = blockIdx.y;
    const int ch_start = (NCHUNK * ks) >> 2;
    const int ch_end = (NCHUNK * (ks + 1)) >> 2;

    // ---- stage z tile ----
    #pragma unroll
    for (int it = 0; it < 4; ++it) {
        int L = tid + it * S_NT;        // 0..511
        int b = L >> 4;                 // 0..31
        int cq = (L & 15) << 2;
        float4 z4 = *(const float4*)&z[(size_t)(row0 + b) * DDIM + cq];
        zs[b][cq + 0] = z4.x; zs[b][cq + 1] = z4.y;
        zs[b][cq + 2] = z4.z; zs[b][cq + 3] = z4.w;
    }
    if (tid < S_BM) { zs[tid][64] = 1.f; zs[tid][65] = 0.f; }
    __syncthreads();

    const int rg = tid >> 4;            // 0..7
    const int cg = tid & 15;            // 0..15
    const int r0 = rg * 4, c0 = cg * 4;
    float acc[4][4] = {};

    for (int ch = ch_start; ch < ch_end; ++ch) {
        const int f0 = ch * S_BK;
        // ---- build theta chunk ----
        #pragma unroll
        for (int i = 0; i < 8; ++i) {
            int e = tid + i * S_NT;
            int b = e & 31;
            int fi = e >> 5;            // 0..31
            int f = f0 + fi;
            ThT[fi][b] = zs[b][iu[f]] * zs[b][ju[f]];
        }
        // ---- stage xi chunk ----
        #pragma unroll
        for (int it = 0; it < 4; ++it) {
            int L = tid + it * S_NT;    // 0..511
            int fr = L >> 4;            // 0..31
            int cq = (L & 15) << 2;
            *(float4*)&XiS[fr][cq] = *(const float4*)&xi[(size_t)(f0 + fr) * DDIM + cq];
        }
        __syncthreads();
        #pragma unroll
        for (int kk = 0; kk < S_BK; ++kk) {
            float4 t4 = *(const float4*)&ThT[kk][r0];
            float4 x4 = *(const float4*)&XiS[kk][c0];
            float tv[4] = { t4.x, t4.y, t4.z, t4.w };
            #pragma unroll
            for (int t = 0; t < 4; ++t) {
                acc[t][0] = fmaf(tv[t], x4.x, acc[t][0]);
                acc[t][1] = fmaf(tv[t], x4.y, acc[t][1]);
                acc[t][2] = fmaf(tv[t], x4.z, acc[t][2]);
                acc[t][3] = fmaf(tv[t], x4.w, acc[t][3]);
            }
        }
        __syncthreads();
    }

    float* po = part + (size_t)ks * BATCH * DDIM;
    #pragma unroll
    for (int t = 0; t < 4; ++t) {
        *(float4*)&po[(size_t)(row0 + r0 + t) * DDIM + c0] =
            make_float4(acc[t][0], acc[t][1], acc[t][2], acc[t][3]);
    }
}

// =====================================================================
extern "C" void kernel_launch(void* const* d_in, const int* in_sizes, int n_in,
                              void* d_out, int out_size, void* d_ws, size_t ws_size,
                              hipStream_t stream)
{
    const float* x    = (const float*)d_in[0];
    const float* xdot = (const float*)d_in[1];
    const float* We1  = (const float*)d_in[2];
    const float* be1  = (const float*)d_in[3];
    const float* We2  = (const float*)d_in[4];
    const float* be2  = (const float*)d_in[5];
    const float* We3  = (const float*)d_in[6];
    const float* be3  = (const float*)d_in[7];
    const float* Wd1  = (const float*)d_in[8];
    const float* bd1  = (const float*)d_in[9];
    const float* Wd2  = (const float*)d_in[10];
    const float* bd2  = (const float*)d_in[11];
    const float* Wd3  = (const float*)d_in[12];
    const float* bd3  = (const float*)d_in[13];
    const float* XI   = (const float*)d_in[14];
    const float* XIm  = (const float*)d_in[15];

    float* out = (float*)d_out;
    float* xh  = out;                                   // [4096,512]
    float* dxh = out + (size_t)BATCH * IN_DIM;          // [4096,512]
    float* zo  = dxh + (size_t)BATCH * IN_DIM;          // [4096,64]
    float* dz  = zo + (size_t)BATCH * DDIM;             // [4096,64]
    float* dzs = dz + (size_t)BATCH * DDIM;             // [4096,64]

    // workspace layout (all 16B aligned)
    int*   iu     = (int*)d_ws;                         // [2112]
    int*   ju     = iu + NFPAD;                         // [2112]
    float* xi_eff = (float*)(ju + NFPAD);               // [2112*64]
    float* h1 = xi_eff + (size_t)NFPAD * DDIM;          // [4096,128]
    float* v1 = h1 + (size_t)BATCH * H1DIM;
    float* h2 = v1 + (size_t)BATCH * H1DIM;             // [4096,64]
    float* v2 = h2 + (size_t)BATCH * H2DIM;
    float* g1 = v2 + (size_t)BATCH * H2DIM;             // [4096,64]
    float* u1 = g1 + (size_t)BATCH * DDIM;
    float* g2 = u1 + (size_t)BATCH * DDIM;              // [4096,128]
    float* u2 = g2 + (size_t)BATCH * H1DIM;
    float* part = u2 + (size_t)BATCH * H1DIM;           // [4][4096,64]
    const int partStride = BATCH * DDIM;

    init_tables<<<132, 256, 0, stream>>>(iu, ju, xi_eff, XI, XIm);

    // encoder
    dual_gemm<false><<<dim3(BATCH / BM, H1DIM / BN), NT, 0, stream>>>(
        x, xdot, We1, be1, h1, v1, nullptr, BATCH, H1DIM, IN_DIM, 0);
    dual_gemm<false><<<dim3(BATCH / BM, 1), NT, 0, stream>>>(
        h1, v1, We2, be2, h2, v2, nullptr, BATCH, H2DIM, H1DIM, 0);
    dual_gemm<false><<<dim3(BATCH / BM, 1), NT, 0, stream>>>(
        h2, v2, We3, be3, zo, dz, nullptr, BATCH, DDIM, H2DIM, 0);

    // SINDy library GEMM (split-K partials)
    sindy_gemm<<<dim3(BATCH / S_BM, 4), S_NT, 0, stream>>>(zo, xi_eff, iu, ju, part);

    // decoder (decL1 sums partials -> dz_dt_sindy, and consumes it as tangent)
    dual_gemm<true><<<dim3(BATCH / BM, 1), NT, 0, stream>>>(
        zo, part, Wd1, bd1, g1, u1, dzs, BATCH, DDIM, DDIM, partStride);
    dual_gemm<false><<<dim3(BATCH / BM, H1DIM / BN), NT, 0, stream>>>(
        g1, u1, Wd2, bd2, g2, u2, nullptr, BATCH, H1DIM, DDIM, 0);
    dual_gemm<false><<<dim3(BATCH / BM, IN_DIM / BN), NT, 0, stream>>>(
        g2, u2, Wd3, bd3, xh, dxh, nullptr, BATCH, IN_DIM, H1DIM, 0);
}

// Round 3
// 71.973 us; speedup vs baseline: 1.7813x; 1.7813x over previous
//
#include <hip/hip_runtime.h>

#define BATCH 4096
#define IN_DIM 512
#define H1DIM 128
#define H2DIM 64
#define DDIM 64
#define NFUNC 2081
#define NFPAD 2112

typedef short bf16x8 __attribute__((ext_vector_type(8)));
typedef float f32x4 __attribute__((ext_vector_type(4)));
#define MFMA(a,b,c) __builtin_amdgcn_mfma_f32_16x16x32_bf16(a,b,c,0,0,0)

#define WSZ1 (H1DIM*IN_DIM)
#define WSZ2 (H2DIM*H1DIM)
#define WSZ3 (DDIM*H2DIM)
#define WSZ4 (H2DIM*DDIM)
#define WSZ5 (H1DIM*H2DIM)
#define WSZ6 (IN_DIM*H1DIM)

__device__ __forceinline__ short f2b(float f) {
    union { float f; unsigned u; } x; x.f = f;
    unsigned r = x.u + 0x7fffu + ((x.u >> 16) & 1u);
    return (short)(r >> 16);
}
__device__ __forceinline__ float b2f(short s) {
    union { unsigned u; float f; } x; x.u = ((unsigned)(unsigned short)s) << 16;
    return x.f;
}
__device__ __forceinline__ void split3f(float v, short& s0, short& s1, short& s2) {
    s0 = f2b(v); float r = v - b2f(s0);
    s1 = f2b(r); float r2 = r - b2f(s1);
    s2 = f2b(r2);
}
__device__ __forceinline__ uint2 pk4(const short* s) {
    union { short s[4]; uint2 u; } z;
    z.s[0] = s[0]; z.s[1] = s[1]; z.s[2] = s[2]; z.s[3] = s[3];
    return z.u;
}

// ---- swizzled LDS tile helpers (row stride RS shorts, byte ^= (r&7)<<4) ----
__device__ __forceinline__ void st_b16(short* t, int RS, int r, int c, short v) {
    int b = (c * 2) ^ ((r & 7) << 4);
    *(short*)((char*)(t + r * RS) + b) = v;
}
__device__ __forceinline__ void st_b64(short* t, int RS, int r, int c0, uint2 v) {
    int b = (c0 * 2) ^ ((r & 7) << 4);
    *(uint2*)((char*)(t + r * RS) + b) = v;
}
__device__ __forceinline__ bf16x8 ld_af(const short* t, int RS, int lane, int kbase) {
    int r = lane & 15;
    int b = ((kbase + (lane >> 4) * 8) * 2) ^ ((r & 7) << 4);
    return *(const bf16x8*)((const char*)(t + r * RS) + b);
}
__device__ __forceinline__ bf16x8 ld_bg(const short* W, int K, int col0, int kbase, int lane) {
    return *(const bf16x8*)(W + (size_t)(col0 + (lane & 15)) * K + kbase + (lane >> 4) * 8);
}

// 8-product split-precision dual layer: primal (f32-grade) + tangent (bf16-grade)
template<int K, int NFRAG>
__device__ __forceinline__ void layer8(const short* a0t, const short* a1t, const short* a2t,
                                       const short* avt, int RS,
                                       const short* W0, int wsz, int col0, int lane,
                                       f32x4* accP, f32x4* accQ, f32x4* accV)
{
    const short* W1 = W0 + wsz;
    const short* W2 = W1 + wsz;
    #pragma unroll
    for (int s = 0; s < K / 32; ++s) {
        bf16x8 f0 = ld_af(a0t, RS, lane, s * 32);
        bf16x8 f1 = ld_af(a1t, RS, lane, s * 32);
        bf16x8 f2 = ld_af(a2t, RS, lane, s * 32);
        bf16x8 fv = ld_af(avt, RS, lane, s * 32);
        #pragma unroll
        for (int nf = 0; nf < NFRAG; ++nf) {
            bf16x8 b0 = ld_bg(W0, K, col0 + nf * 16, s * 32, lane);
            bf16x8 b1 = ld_bg(W1, K, col0 + nf * 16, s * 32, lane);
            bf16x8 b2 = ld_bg(W2, K, col0 + nf * 16, s * 32, lane);
            accP[nf] = MFMA(f0, b0, accP[nf]);
            accQ[nf] = MFMA(f1, b1, accQ[nf]);
            accP[nf] = MFMA(f1, b0, accP[nf]);
            accQ[nf] = MFMA(f0, b1, accQ[nf]);
            accP[nf] = MFMA(f2, b0, accP[nf]);
            accQ[nf] = MFMA(f2, b1, accQ[nf]);
            accP[nf] = MFMA(f0, b2, accP[nf]);
            accQ[nf] = MFMA(f1, b2, accQ[nf]);
            accV[nf] = MFMA(fv, b0, accV[nf]);
        }
    }
}

// epilogue: pre = P+Q+bias; store 3 relu splits + masked tangent bf16
__device__ __forceinline__ void epi_store(short* t0, short* t1, short* t2, short* tv, int RS,
                                          int lane, int col, const f32x4& P, const f32x4& Q,
                                          const f32x4& V, float bb)
{
    #pragma unroll
    for (int q = 0; q < 4; ++q) {
        int row = (lane >> 4) * 4 + q;
        float pre = P[q] + Q[q] + bb;
        float h = fmaxf(pre, 0.f);
        short s0, s1, s2;
        split3f(h, s0, s1, s2);
        st_b16(t0, RS, row, col, s0);
        st_b16(t1, RS, row, col, s1);
        st_b16(t2, RS, row, col, s2);
        st_b16(tv, RS, row, col, pre > 0.f ? f2b(V[q]) : (short)0);
    }
}

// =====================================================================
__global__ void initk(const float* __restrict__ We1, const float* __restrict__ We2,
                      const float* __restrict__ We3, const float* __restrict__ Wd1,
                      const float* __restrict__ Wd2, const float* __restrict__ Wd3,
                      const float* __restrict__ XI, const float* __restrict__ XIm,
                      short* Wb1, short* Wb2, short* Wb3, short* Wb4, short* Wb5, short* Wb6,
                      short* xiT, int2* pk)
{
    int gid = blockIdx.x * blockDim.x + threadIdx.x;
    int nthr = gridDim.x * blockDim.x;
    for (int i = gid; i < WSZ1; i += nthr) { short a,b,c; split3f(We1[i],a,b,c); Wb1[i]=a; Wb1[i+WSZ1]=b; Wb1[i+2*WSZ1]=c; }
    for (int i = gid; i < WSZ2; i += nthr) { short a,b,c; split3f(We2[i],a,b,c); Wb2[i]=a; Wb2[i+WSZ2]=b; Wb2[i+2*WSZ2]=c; }
    for (int i = gid; i < WSZ3; i += nthr) { short a,b,c; split3f(We3[i],a,b,c); Wb3[i]=a; Wb3[i+WSZ3]=b; Wb3[i+2*WSZ3]=c; }
    for (int i = gid; i < WSZ4; i += nthr) { short a,b,c; split3f(Wd1[i],a,b,c); Wb4[i]=a; Wb4[i+WSZ4]=b; Wb4[i+2*WSZ4]=c; }
    for (int i = gid; i < WSZ5; i += nthr) { short a,b,c; split3f(Wd2[i],a,b,c); Wb5[i]=a; Wb5[i+WSZ5]=b; Wb5[i+2*WSZ5]=c; }
    for (int i = gid; i < WSZ6; i += nthr) { short a,b,c; split3f(Wd3[i],a,b,c); Wb6[i]=a; Wb6[i+WSZ6]=b; Wb6[i+2*WSZ6]=c; }
    for (int i = gid; i < DDIM * NFPAD; i += nthr) {
        int c = i / NFPAD, k = i - c * NFPAD;
        float v = (k < NFUNC) ? XI[k * DDIM + c] * XIm[k * DDIM + c] : 0.f;
        xiT[i] = f2b(v);
    }
    for (int f = gid; f < NFPAD; f += nthr) {
        int a, b;
        if (f == 0) { a = 64; b = 64; }
        else if (f <= DDIM) { a = f - 1; b = 64; }
        else if (f < NFUNC) {
            int p = f - 1 - DDIM; int i2 = 0, cum = 0;
            while (cum + (63 - i2) <= p) { cum += 63 - i2; ++i2; }
            a = i2; b = i2 + 1 + (p - cum);
        } else { a = 65; b = 65; }
        pk[f] = make_int2(a, b);
    }
}

// =====================================================================
__global__ __launch_bounds__(256, 1)
void fused(const float* __restrict__ x, const float* __restrict__ xdot,
           const float* __restrict__ be1, const float* __restrict__ be2,
           const float* __restrict__ be3, const float* __restrict__ bd1,
           const float* __restrict__ bd2, const float* __restrict__ bd3,
           const short* __restrict__ Wb1, const short* __restrict__ Wb2,
           const short* __restrict__ Wb3, const short* __restrict__ Wb4,
           const short* __restrict__ Wb5, const short* __restrict__ Wb6,
           const short* __restrict__ xiT, const int2* __restrict__ pk,
           float* __restrict__ xh, float* __restrict__ dxh, float* __restrict__ zo,
           float* __restrict__ dz, float* __restrict__ dzs)
{
    // LDS regions aliased by lifetime (total 43264 B):
    // A @ 0     : xs0,xs1,xs2,xds (4x2048)   -> later g1s0,g1s1,g1s2,u1
    // B @ 8192  : h1s0,h1s1,h1s2,v1 (4x4096) -> later g2s0,g2s1,g2s2,u2
    // C @ 24576 : h2s0,h2s1,h2s2,v2 (4x2048) -> later th@24576, dzsb@26624
    // D @ 32768 : zb0,zb1,zb2 (3x2048), zf f32 (4352)
    __shared__ __align__(16) char ldsbuf[43264];
    short* xs0 = (short*)(ldsbuf + 0);
    short* xs1 = (short*)(ldsbuf + 2048);
    short* xs2 = (short*)(ldsbuf + 4096);
    short* xds = (short*)(ldsbuf + 6144);
    short* g1s0 = xs0; short* g1s1 = xs1; short* g1s2 = xs2; short* u1 = xds;
    short* h1s0 = (short*)(ldsbuf + 8192);
    short* h1s1 = (short*)(ldsbuf + 12288);
    short* h1s2 = (short*)(ldsbuf + 16384);
    short* v1   = (short*)(ldsbuf + 20480);
    short* g2s0 = h1s0; short* g2s1 = h1s1; short* g2s2 = h1s2; short* u2 = v1;
    short* h2s0 = (short*)(ldsbuf + 24576);
    short* h2s1 = (short*)(ldsbuf + 26624);
    short* h2s2 = (short*)(ldsbuf + 28672);
    short* v2   = (short*)(ldsbuf + 30720);
    short* th   = h2s0;   // alias (h2 dead after L3)
    short* dzsb = h2s1;   // alias
    short* zb0 = (short*)(ldsbuf + 32768);
    short* zb1 = (short*)(ldsbuf + 34816);
    short* zb2 = (short*)(ldsbuf + 36864);
    float* zf  = (float*)(ldsbuf + 38912);  // [16][68]

    const int tid = threadIdx.x, lane = tid & 63, wave = tid >> 6;
    const int row0 = blockIdx.x * 16;
    const int sr = tid >> 4, sc4 = (tid & 15) * 4;

    // ---------------- encoder L1 (K=512, N=128), streamed in 8 chunks ----------------
    f32x4 accP[2] = {}, accQ[2] = {}, accV[2] = {};
    const float* xrow  = x    + (size_t)(row0 + sr) * IN_DIM + sc4;
    const float* xdrow = xdot + (size_t)(row0 + sr) * IN_DIM + sc4;
    f32x4 pxa[2], pxd[2];
    pxa[0] = *(const f32x4*)xrow;
    pxd[0] = *(const f32x4*)xdrow;
    #pragma unroll
    for (int c = 0; c < 8; ++c) {
        short a0[4], a1[4], a2[4], d0[4];
        #pragma unroll
        for (int e = 0; e < 4; ++e) {
            split3f(pxa[c & 1][e], a0[e], a1[e], a2[e]);
            d0[e] = f2b(pxd[c & 1][e]);
        }
        st_b64(xs0, 64, sr, sc4, pk4(a0));
        st_b64(xs1, 64, sr, sc4, pk4(a1));
        st_b64(xs2, 64, sr, sc4, pk4(a2));
        st_b64(xds, 64, sr, sc4, pk4(d0));
        __syncthreads();
        if (c < 7) {
            pxa[(c + 1) & 1] = *(const f32x4*)(xrow + (c + 1) * 64);
            pxd[(c + 1) & 1] = *(const f32x4*)(xdrow + (c + 1) * 64);
        }
        #pragma unroll
        for (int s = 0; s < 2; ++s) {
            bf16x8 f0 = ld_af(xs0, 64, lane, s * 32);
            bf16x8 f1 = ld_af(xs1, 64, lane, s * 32);
            bf16x8 f2 = ld_af(xs2, 64, lane, s * 32);
            bf16x8 fv = ld_af(xds, 64, lane, s * 32);
            #pragma unroll
            for (int nf = 0; nf < 2; ++nf) {
                int col0 = wave * 32 + nf * 16;
                int kb = c * 64 + s * 32;
                bf16x8 b0 = ld_bg(Wb1, IN_DIM, col0, kb, lane);
                bf16x8 b1 = ld_bg(Wb1 + WSZ1, IN_DIM, col0, kb, lane);
                bf16x8 b2 = ld_bg(Wb1 + 2 * WSZ1, IN_DIM, col0, kb, lane);
                accP[nf] = MFMA(f0, b0, accP[nf]);
                accQ[nf] = MFMA(f1, b1, accQ[nf]);
                accP[nf] = MFMA(f1, b0, accP[nf]);
                accQ[nf] = MFMA(f0, b1, accQ[nf]);
                accP[nf] = MFMA(f2, b0, accP[nf]);
                accQ[nf] = MFMA(f2, b1, accQ[nf]);
                accP[nf] = MFMA(f0, b2, accP[nf]);
                accQ[nf] = MFMA(f1, b2, accQ[nf]);
                accV[nf] = MFMA(fv, b0, accV[nf]);
            }
        }
        __syncthreads();
    }
    #pragma unroll
    for (int nf = 0; nf < 2; ++nf) {
        int col = wave * 32 + nf * 16 + (lane & 15);
        epi_store(h1s0, h1s1, h1s2, v1, 128, lane, col, accP[nf], accQ[nf], accV[nf], be1[col]);
    }
    __syncthreads();

    // ---------------- encoder L2 (K=128, N=64) ----------------
    {
        f32x4 P[1] = {}, Q[1] = {}, V[1] = {};
        layer8<128, 1>(h1s0, h1s1, h1s2, v1, 128, Wb2, WSZ2, wave * 16, lane, P, Q, V);
        int col = wave * 16 + (lane & 15);
        epi_store(h2s0, h2s1, h2s2, v2, 64, lane, col, P[0], Q[0], V[0], be2[col]);
    }
    __syncthreads();

    // ---------------- encoder L3 (K=64, N=64) -> z, dz ----------------
    {
        f32x4 P[1] = {}, Q[1] = {}, V[1] = {};
        layer8<64, 1>(h2s0, h2s1, h2s2, v2, 64, Wb3, WSZ3, wave * 16, lane, P, Q, V);
        int col = wave * 16 + (lane & 15);
        float bb = be3[col];
        #pragma unroll
        for (int q = 0; q < 4; ++q) {
            int row = (lane >> 4) * 4 + q;
            float pre = P[0][q] + Q[0][q] + bb;
            float hz = fmaxf(pre, 0.f);
            float vz = pre > 0.f ? V[0][q] : 0.f;
            zf[row * 68 + col] = hz;
            short s0, s1, s2;
            split3f(hz, s0, s1, s2);
            st_b16(zb0, 64, row, col, s0);
            st_b16(zb1, 64, row, col, s1);
            st_b16(zb2, 64, row, col, s2);
            zo[(size_t)(row0 + row) * DDIM + col] = hz;
            dz[(size_t)(row0 + row) * DDIM + col] = vz;
        }
    }
    if (tid < 32) { int r = tid & 15; zf[r * 68 + 64 + (tid >> 4)] = (tid >> 4) ? 0.f : 1.f; }
    __syncthreads();

    // ---------------- SINDy: dzs = theta(z_f32) @ xi (K=2112, N=64) ----------------
    f32x4 sacc = {};
    const int tr = tid & 15, tf = (tid >> 4) * 4;
    for (int ch = 0; ch < 33; ++ch) {
        int f0 = ch * 64;
        bf16x8 b0 = ld_bg(xiT, NFPAD, wave * 16, f0, lane);
        bf16x8 b1 = ld_bg(xiT, NFPAD, wave * 16, f0 + 32, lane);
        #pragma unroll
        for (int j = 0; j < 4; ++j) {
            int f = f0 + tf + j;
            int2 p = pk[f];
            float t1 = zf[tr * 68 + p.x] * zf[tr * 68 + p.y];
            st_b16(th, 64, tr, tf + j, f2b(t1));
        }
        __syncthreads();
        bf16x8 a0 = ld_af(th, 64, lane, 0);
        bf16x8 a1 = ld_af(th, 64, lane, 32);
        sacc = MFMA(a0, b0, sacc);
        sacc = MFMA(a1, b1, sacc);
        __syncthreads();
    }
    {
        int col = wave * 16 + (lane & 15);
        #pragma unroll
        for (int q = 0; q < 4; ++q) {
            int row = (lane >> 4) * 4 + q;
            float v = sacc[q];
            dzs[(size_t)(row0 + row) * DDIM + col] = v;
            st_b16(dzsb, 64, row, col, f2b(v));
        }
    }
    __syncthreads();

    // ---------------- decoder L1 (K=64, N=64) ----------------
    {
        f32x4 P[1] = {}, Q[1] = {}, V[1] = {};
        layer8<64, 1>(zb0, zb1, zb2, dzsb, 64, Wb4, WSZ4, wave * 16, lane, P, Q, V);
        int col = wave * 16 + (lane & 15);
        epi_store(g1s0, g1s1, g1s2, u1, 64, lane, col, P[0], Q[0], V[0], bd1[col]);
    }
    __syncthreads();

    // ---------------- decoder L2 (K=64, N=128) ----------------
    {
        f32x4 P[2] = {}, Q[2] = {}, V[2] = {};
        layer8<64, 2>(g1s0, g1s1, g1s2, u1, 64, Wb5, WSZ5, wave * 32, lane, P, Q, V);
        #pragma unroll
        for (int nf = 0; nf < 2; ++nf) {
            int col = wave * 32 + nf * 16 + (lane & 15);
            epi_store(g2s0, g2s1, g2s2, u2, 128, lane, col, P[nf], Q[nf], V[nf], bd2[col]);
        }
    }
    __syncthreads();

    // ---------------- decoder L3 (K=128, N=512) -> xh, dxh ----------------
    #pragma unroll
    for (int h = 0; h < 2; ++h) {
        f32x4 P[4] = {}, Q[4] = {}, V[4] = {};
        layer8<128, 4>(g2s0, g2s1, g2s2, u2, 128, Wb6, WSZ6, wave * 128 + h * 64, lane, P, Q, V);
        #pragma unroll
        for (int nf = 0; nf < 4; ++nf) {
            int col = wave * 128 + h * 64 + nf * 16 + (lane & 15);
            float bb = bd3[col];
            #pragma unroll
            for (int q = 0; q < 4; ++q) {
                int row = (lane >> 4) * 4 + q;
                float pre = P[nf][q] + Q[nf][q] + bb;
                xh[(size_t)(row0 + row) * IN_DIM + col] = fmaxf(pre, 0.f);
                dxh[(size_t)(row0 + row) * IN_DIM + col] = pre > 0.f ? V[nf][q] : 0.f;
            }
        }
    }
}

// =====================================================================
extern "C" void kernel_launch(void* const* d_in, const int* in_sizes, int n_in,
                              void* d_out, int out_size, void* d_ws, size_t ws_size,
                              hipStream_t stream)
{
    const float* x    = (const float*)d_in[0];
    const float* xdot = (const float*)d_in[1];
    const float* We1  = (const float*)d_in[2];
    const float* be1  = (const float*)d_in[3];
    const float* We2  = (const float*)d_in[4];
    const float* be2  = (const float*)d_in[5];
    const float* We3  = (const float*)d_in[6];
    const float* be3  = (const float*)d_in[7];
    const float* Wd1  = (const float*)d_in[8];
    const float* bd1  = (const float*)d_in[9];
    const float* Wd2  = (const float*)d_in[10];
    const float* bd2  = (const float*)d_in[11];
    const float* Wd3  = (const float*)d_in[12];
    const float* bd3  = (const float*)d_in[13];
    const float* XI   = (const float*)d_in[14];
    const float* XIm  = (const float*)d_in[15];

    float* out = (float*)d_out;
    float* xh  = out;
    float* dxh = out + (size_t)BATCH * IN_DIM;
    float* zo  = dxh + (size_t)BATCH * IN_DIM;
    float* dz  = zo + (size_t)BATCH * DDIM;
    float* dzs = dz + (size_t)BATCH * DDIM;

    // ws layout: pk, 3-plane bf16 weight splits, xiT
    int2*  pk  = (int2*)d_ws;                      // [2112]
    short* Wb1 = (short*)(pk + NFPAD);
    short* Wb2 = Wb1 + 3 * WSZ1;
    short* Wb3 = Wb2 + 3 * WSZ2;
    short* Wb4 = Wb3 + 3 * WSZ3;
    short* Wb5 = Wb4 + 3 * WSZ4;
    short* Wb6 = Wb5 + 3 * WSZ5;
    short* xiT = Wb6 + 3 * WSZ6;                   // [64][2112]

    initk<<<256, 256, 0, stream>>>(We1, We2, We3, Wd1, Wd2, Wd3, XI, XIm,
                                   Wb1, Wb2, Wb3, Wb4, Wb5, Wb6, xiT, pk);
    fused<<<BATCH / 16, 256, 0, stream>>>(x, xdot, be1, be2, be3, bd1, bd2, bd3,
                                          Wb1, Wb2, Wb3, Wb4, Wb5, Wb6, xiT, pk,
                                          xh, dxh, zo, dz, dzs);
}